// Round 2
// baseline (144.789 us; speedup 1.0000x reference)
//
#include <hip/hip_runtime.h>

// Loss = mean(0.5*(o-t)^2 * ef(t)) over N = 64*1*512*512 = 2^24 fp32 elements.
// ef(t) = BETA - exp((A-1)*ln(x) - x + BIAS),  x = (t - LOC)/SCALE
// History: R1-R5 coherent reads pinned 3.0 TB/s regardless of MLP/occupancy.
// R6 all-NT: 3.7 TB/s (~36us). R7 out=NT/tgt=cached: 4.3 TB/s (~31us).
// R8 (measured R1 of this session): monolithic interleaved asm + staged
// vmcnt(14-2r) -> 41.3us REGRESSION; FETCH=64MiB proves tgt is IF$-resident
// and nt keeps out OFF the IF$ (HBM re-stream every iter).
// R9: out-loads nt -> sc1 (bypass per-XCD L2 but allow memory-side IF$
// allocation; both arrays = 128MiB <= 256MiB IF$) + single vmcnt(0)
// consumption (de-stage, R7-style). Discriminator: FETCH_SIZE -> ~0 means
// sc1 allocates IF$; stays 64MiB means sc1 ~ nt.

#define NBLOCKS 2048
#define NTHREADS 256
#define F4_PER_THREAD 8   // 2048*256*8*4 = 2^24 elements exactly

__device__ __forceinline__ float ef_term(float o, float y) {
    constexpr float A_M1      = -0.93555708575356741f;  // EST_A - 1
    constexpr float NEG_LOC   =  1.1328205299926424e-27f;
    constexpr float INV_SCALE =  0.65034886603218541f;  // 1/1.5376362609160314
    constexpr float BIAS      = -56.8416699f;
    constexpr float BETA      =  5.0f;

    float x  = (y + NEG_LOC) * INV_SCALE;           // > 0 for y >= 0
    float ex = __expf(fmaf(A_M1, __logf(x), BIAS - x));
    float ef = BETA - ex;                            // == c when y == 0
    float d  = o - y;
    return 0.5f * d * d * ef;
}

// s_waitcnt vmcnt(N), then materialize an opaque 0 in a VGPR. Consumers OR
// their bits with the result -> cannot be hoisted above the wait.
template <int N>
__device__ __forceinline__ unsigned waitcnt_vm_zero() {
    unsigned g;
    asm volatile("s_waitcnt vmcnt(%1)\n\tv_mov_b32 %0, 0"
                 : "=v"(g) : "n"(N) : "memory");
    return g;
}

__device__ __forceinline__ float guard(float v, unsigned g) {
    return __uint_as_float(__float_as_uint(v) | g);
}

__device__ __forceinline__ float block_reduce(float acc) {
    #pragma unroll
    for (int off = 32; off > 0; off >>= 1)
        acc += __shfl_down(acc, off, 64);
    __shared__ float wsum[NTHREADS / 64];
    int lane = threadIdx.x & 63;
    int wave = threadIdx.x >> 6;
    if (lane == 0) wsum[wave] = acc;
    __syncthreads();
    float s = 0.f;
    if (threadIdx.x == 0) {
        #pragma unroll
        for (int w = 0; w < NTHREADS / 64; ++w) s += wsum[w];
    }
    return s;  // valid on thread 0 only
}

// Fast path: n == NBLOCKS*NTHREADS*F4_PER_THREAD*4 exactly.
// Round r fully coalesced: float4 index = chunk_base + r*NTHREADS + tid.
// All 16 loads issued in ONE asm block: 8 o-loads first (sc1: bypass L2,
// IF$-allocating), then 8 t-loads (cached). Single vmcnt(0) before compute.
__global__ __launch_bounds__(NTHREADS, 2) void ef_loss_partial_fast(
    const float* __restrict__ out, const float* __restrict__ tgt,
    float* __restrict__ partials) {
    const int base = blockIdx.x * (NTHREADS * F4_PER_THREAD) + threadIdx.x;
    const float4* __restrict__ op = (const float4*)out;
    const float4* __restrict__ tp = (const float4*)tgt;

    const float4 *po0 = op + base,                *pt0 = tp + base;
    const float4 *po1 = op + base + 1 * NTHREADS, *pt1 = tp + base + 1 * NTHREADS;
    const float4 *po2 = op + base + 2 * NTHREADS, *pt2 = tp + base + 2 * NTHREADS;
    const float4 *po3 = op + base + 3 * NTHREADS, *pt3 = tp + base + 3 * NTHREADS;
    const float4 *po4 = op + base + 4 * NTHREADS, *pt4 = tp + base + 4 * NTHREADS;
    const float4 *po5 = op + base + 5 * NTHREADS, *pt5 = tp + base + 5 * NTHREADS;
    const float4 *po6 = op + base + 6 * NTHREADS, *pt6 = tp + base + 6 * NTHREADS;
    const float4 *po7 = op + base + 7 * NTHREADS, *pt7 = tp + base + 7 * NTHREADS;

    float4 o0, o1, o2, o3, o4v, o5, o6, o7;
    float4 t0, t1, t2, t3, t4v, t5, t6, t7;

    asm volatile(
        "global_load_dwordx4 %0, %16, off sc1\n\t"
        "global_load_dwordx4 %1, %17, off sc1\n\t"
        "global_load_dwordx4 %2, %18, off sc1\n\t"
        "global_load_dwordx4 %3, %19, off sc1\n\t"
        "global_load_dwordx4 %4, %20, off sc1\n\t"
        "global_load_dwordx4 %5, %21, off sc1\n\t"
        "global_load_dwordx4 %6, %22, off sc1\n\t"
        "global_load_dwordx4 %7, %23, off sc1\n\t"
        "global_load_dwordx4 %8, %24, off\n\t"
        "global_load_dwordx4 %9, %25, off\n\t"
        "global_load_dwordx4 %10, %26, off\n\t"
        "global_load_dwordx4 %11, %27, off\n\t"
        "global_load_dwordx4 %12, %28, off\n\t"
        "global_load_dwordx4 %13, %29, off\n\t"
        "global_load_dwordx4 %14, %30, off\n\t"
        "global_load_dwordx4 %15, %31, off"
        : "=&v"(o0), "=&v"(o1), "=&v"(o2), "=&v"(o3),
          "=&v"(o4v), "=&v"(o5), "=&v"(o6), "=&v"(o7),
          "=&v"(t0), "=&v"(t1), "=&v"(t2), "=&v"(t3),
          "=&v"(t4v), "=&v"(t5), "=&v"(t6), "=&v"(t7)
        : "v"(po0), "v"(po1), "v"(po2), "v"(po3),
          "v"(po4), "v"(po5), "v"(po6), "v"(po7),
          "v"(pt0), "v"(pt1), "v"(pt2), "v"(pt3),
          "v"(pt4), "v"(pt5), "v"(pt6), "v"(pt7)
        : "memory");

    float a0 = 0.f, a1 = 0.f, a2 = 0.f, a3 = 0.f;

    unsigned g = waitcnt_vm_zero<0>();

#define EF_ROUND(ov, tv)                                                    \
    do {                                                                    \
        a0 += ef_term(guard(ov.x, g), guard(tv.x, g));                      \
        a1 += ef_term(guard(ov.y, g), guard(tv.y, g));                      \
        a2 += ef_term(guard(ov.z, g), guard(tv.z, g));                      \
        a3 += ef_term(guard(ov.w, g), guard(tv.w, g));                      \
    } while (0)

    EF_ROUND(o0, t0);
    EF_ROUND(o1, t1);
    EF_ROUND(o2, t2);
    EF_ROUND(o3, t3);
    EF_ROUND(o4v, t4v);
    EF_ROUND(o5, t5);
    EF_ROUND(o6, t6);
    EF_ROUND(o7, t7);
#undef EF_ROUND

    float s = block_reduce((a0 + a1) + (a2 + a3));
    if (threadIdx.x == 0) partials[blockIdx.x] = s;
}

// Generic fallback (any n).
__global__ __launch_bounds__(NTHREADS) void ef_loss_partial_gen(
    const float* __restrict__ out, const float* __restrict__ tgt,
    float* __restrict__ partials, int n) {
    const int idx    = blockIdx.x * blockDim.x + threadIdx.x;
    const int stride = gridDim.x * blockDim.x;
    const int n4     = n >> 2;
    const float4* __restrict__ o4 = (const float4*)out;
    const float4* __restrict__ t4 = (const float4*)tgt;

    float acc = 0.f;
    for (int i = idx; i < n4; i += stride) {
        float4 o = o4[i];
        float4 t = t4[i];
        acc += ef_term(o.x, t.x);
        acc += ef_term(o.y, t.y);
        acc += ef_term(o.z, t.z);
        acc += ef_term(o.w, t.w);
    }
    for (int i = (n4 << 2) + idx; i < n; i += stride)
        acc += ef_term(out[i], tgt[i]);

    float s = block_reduce(acc);
    if (threadIdx.x == 0) partials[blockIdx.x] = s;
}

__global__ __launch_bounds__(NTHREADS) void ef_loss_finalize(
    const float* __restrict__ partials, float* __restrict__ result,
    int nblocks, float inv_n) {
    float acc = 0.f;
    for (int i = threadIdx.x; i < nblocks; i += blockDim.x)
        acc += partials[i];
    float s = block_reduce(acc);
    if (threadIdx.x == 0) result[0] = s * inv_n;
}

extern "C" void kernel_launch(void* const* d_in, const int* in_sizes, int n_in,
                              void* d_out, int out_size, void* d_ws, size_t ws_size,
                              hipStream_t stream) {
    const float* out_p = (const float*)d_in[0];   // "output"
    const float* tgt_p = (const float*)d_in[1];   // "target"
    float* partials = (float*)d_ws;               // NBLOCKS floats = 8 KB
    float* result   = (float*)d_out;
    const int n = in_sizes[0];

    if (n == NBLOCKS * NTHREADS * F4_PER_THREAD * 4) {
        ef_loss_partial_fast<<<NBLOCKS, NTHREADS, 0, stream>>>(out_p, tgt_p, partials);
    } else {
        ef_loss_partial_gen<<<NBLOCKS, NTHREADS, 0, stream>>>(out_p, tgt_p, partials, n);
    }
    ef_loss_finalize<<<1, NTHREADS, 0, stream>>>(partials, result, NBLOCKS,
                                                 1.0f / (float)n);
}

// Round 3
// 131.624 us; speedup vs baseline: 1.1000x; 1.1000x over previous
//
#include <hip/hip_runtime.h>

// Loss = mean(0.5*(o-t)^2 * ef(t)) over N = 64*1*512*512 = 2^24 fp32 elements.
// ef(t) = BETA - exp((A-1)*ln(x) - x + BIAS),  x = (t - LOC)/SCALE
// Path model (measured): coherent reads pin ~3.0 TB/s (even IF$-resident);
// NT/HBM ~3.7; combined ~4.3 (shared fabric). tgt IS IF$-resident across
// iters (FETCH=64MiB = out only). nt AND sc1 both do NOT allocate IF$ (R9).
// R8 (41.3us) + R9 (44.9us): monolithic 16-load asm block REGRESSES vs R7
// (~31us) regardless of drain style -> the monolith itself (16 dests + 16
// addr pairs pinned live, no compiler scheduling freedom) is the problem.
// R10: revert to R7-style: t = plain compiler float4 loads (cached,
// IF$-allocating), o = 8 SEPARATE single-instruction nt asm loads
// (volatile blocks keep order among themselves; compiler interleaves its
// t-loads/addr-gen freely), single vmcnt(0) guard before consumption
// (mixed-load waits can only over-wait -> correct). Plus launch_bounds
// (256,4): NT path never ran at 4 blocks/CU; ~100 live VGPRs < 128 cap.
// Predict: ~31us recovery, 26-29 if occupancy lifts NT; FETCH ~64MiB.

#define NBLOCKS 2048
#define NTHREADS 256
#define F4_PER_THREAD 8   // 2048*256*8*4 = 2^24 elements exactly

__device__ __forceinline__ float ef_term(float o, float y) {
    constexpr float A_M1      = -0.93555708575356741f;  // EST_A - 1
    constexpr float NEG_LOC   =  1.1328205299926424e-27f;
    constexpr float INV_SCALE =  0.65034886603218541f;  // 1/1.5376362609160314
    constexpr float BIAS      = -56.8416699f;
    constexpr float BETA      =  5.0f;

    float x  = (y + NEG_LOC) * INV_SCALE;           // > 0 for y >= 0
    float ex = __expf(fmaf(A_M1, __logf(x), BIAS - x));
    float ef = BETA - ex;                            // == c when y == 0
    float d  = o - y;
    return 0.5f * d * d * ef;
}

// Single NT (non-allocating, HBM-stream) float4 load as its own asm block.
__device__ __forceinline__ float4 load_nt(const float4* p) {
    float4 v;
    asm volatile("global_load_dwordx4 %0, %1, off nt"
                 : "=v"(v) : "v"(p) : "memory");
    return v;
}

// s_waitcnt vmcnt(N), then materialize an opaque 0 in a VGPR. Consumers OR
// their bits with the result -> cannot be hoisted above the wait.
template <int N>
__device__ __forceinline__ unsigned waitcnt_vm_zero() {
    unsigned g;
    asm volatile("s_waitcnt vmcnt(%1)\n\tv_mov_b32 %0, 0"
                 : "=v"(g) : "n"(N) : "memory");
    return g;
}

__device__ __forceinline__ float guard(float v, unsigned g) {
    return __uint_as_float(__float_as_uint(v) | g);
}

__device__ __forceinline__ float block_reduce(float acc) {
    #pragma unroll
    for (int off = 32; off > 0; off >>= 1)
        acc += __shfl_down(acc, off, 64);
    __shared__ float wsum[NTHREADS / 64];
    int lane = threadIdx.x & 63;
    int wave = threadIdx.x >> 6;
    if (lane == 0) wsum[wave] = acc;
    __syncthreads();
    float s = 0.f;
    if (threadIdx.x == 0) {
        #pragma unroll
        for (int w = 0; w < NTHREADS / 64; ++w) s += wsum[w];
    }
    return s;  // valid on thread 0 only
}

// Fast path: n == NBLOCKS*NTHREADS*F4_PER_THREAD*4 exactly.
// Round r fully coalesced: float4 index = chunk_base + r*NTHREADS + tid.
__global__ __launch_bounds__(NTHREADS, 4) void ef_loss_partial_fast(
    const float* __restrict__ out, const float* __restrict__ tgt,
    float* __restrict__ partials) {
    const int base = blockIdx.x * (NTHREADS * F4_PER_THREAD) + threadIdx.x;
    const float4* __restrict__ op = (const float4*)out;
    const float4* __restrict__ tp = (const float4*)tgt;

    // Issue: per round, one cached t-load (compiler-scheduled) and one nt
    // o-load (own asm block). Volatile asm keeps o-load order; the compiler
    // is free to interleave t-loads and address-gen between them.
    float4 t0 = tp[base + 0 * NTHREADS];
    float4 o0 = load_nt(op + base + 0 * NTHREADS);
    float4 t1 = tp[base + 1 * NTHREADS];
    float4 o1 = load_nt(op + base + 1 * NTHREADS);
    float4 t2 = tp[base + 2 * NTHREADS];
    float4 o2 = load_nt(op + base + 2 * NTHREADS);
    float4 t3 = tp[base + 3 * NTHREADS];
    float4 o3 = load_nt(op + base + 3 * NTHREADS);
    float4 t4v = tp[base + 4 * NTHREADS];
    float4 o4v = load_nt(op + base + 4 * NTHREADS);
    float4 t5 = tp[base + 5 * NTHREADS];
    float4 o5 = load_nt(op + base + 5 * NTHREADS);
    float4 t6 = tp[base + 6 * NTHREADS];
    float4 o6 = load_nt(op + base + 6 * NTHREADS);
    float4 t7 = tp[base + 7 * NTHREADS];
    float4 o7 = load_nt(op + base + 7 * NTHREADS);

    float a0 = 0.f, a1 = 0.f, a2 = 0.f, a3 = 0.f;

    unsigned g = waitcnt_vm_zero<0>();

#define EF_ROUND(ov, tv)                                                    \
    do {                                                                    \
        a0 += ef_term(guard(ov.x, g), guard(tv.x, g));                      \
        a1 += ef_term(guard(ov.y, g), guard(tv.y, g));                      \
        a2 += ef_term(guard(ov.z, g), guard(tv.z, g));                      \
        a3 += ef_term(guard(ov.w, g), guard(tv.w, g));                      \
    } while (0)

    EF_ROUND(o0, t0);
    EF_ROUND(o1, t1);
    EF_ROUND(o2, t2);
    EF_ROUND(o3, t3);
    EF_ROUND(o4v, t4v);
    EF_ROUND(o5, t5);
    EF_ROUND(o6, t6);
    EF_ROUND(o7, t7);
#undef EF_ROUND

    float s = block_reduce((a0 + a1) + (a2 + a3));
    if (threadIdx.x == 0) partials[blockIdx.x] = s;
}

// Generic fallback (any n).
__global__ __launch_bounds__(NTHREADS) void ef_loss_partial_gen(
    const float* __restrict__ out, const float* __restrict__ tgt,
    float* __restrict__ partials, int n) {
    const int idx    = blockIdx.x * blockDim.x + threadIdx.x;
    const int stride = gridDim.x * blockDim.x;
    const int n4     = n >> 2;
    const float4* __restrict__ o4 = (const float4*)out;
    const float4* __restrict__ t4 = (const float4*)tgt;

    float acc = 0.f;
    for (int i = idx; i < n4; i += stride) {
        float4 o = o4[i];
        float4 t = t4[i];
        acc += ef_term(o.x, t.x);
        acc += ef_term(o.y, t.y);
        acc += ef_term(o.z, t.z);
        acc += ef_term(o.w, t.w);
    }
    for (int i = (n4 << 2) + idx; i < n; i += stride)
        acc += ef_term(out[i], tgt[i]);

    float s = block_reduce(acc);
    if (threadIdx.x == 0) partials[blockIdx.x] = s;
}

__global__ __launch_bounds__(NTHREADS) void ef_loss_finalize(
    const float* __restrict__ partials, float* __restrict__ result,
    int nblocks, float inv_n) {
    float acc = 0.f;
    for (int i = threadIdx.x; i < nblocks; i += blockDim.x)
        acc += partials[i];
    float s = block_reduce(acc);
    if (threadIdx.x == 0) result[0] = s * inv_n;
}

extern "C" void kernel_launch(void* const* d_in, const int* in_sizes, int n_in,
                              void* d_out, int out_size, void* d_ws, size_t ws_size,
                              hipStream_t stream) {
    const float* out_p = (const float*)d_in[0];   // "output"
    const float* tgt_p = (const float*)d_in[1];   // "target"
    float* partials = (float*)d_ws;               // NBLOCKS floats = 8 KB
    float* result   = (float*)d_out;
    const int n = in_sizes[0];

    if (n == NBLOCKS * NTHREADS * F4_PER_THREAD * 4) {
        ef_loss_partial_fast<<<NBLOCKS, NTHREADS, 0, stream>>>(out_p, tgt_p, partials);
    } else {
        ef_loss_partial_gen<<<NBLOCKS, NTHREADS, 0, stream>>>(out_p, tgt_p, partials, n);
    }
    ef_loss_finalize<<<1, NTHREADS, 0, stream>>>(partials, result, NBLOCKS,
                                                 1.0f / (float)n);
}